// Round 12
// baseline (15504.385 us; speedup 1.0000x reference)
//
#include <hip/hip_runtime.h>
#include <cstdint>
#include <cstddef>

typedef __bf16 bf16x8 __attribute__((ext_vector_type(8)));
typedef float f32x4 __attribute__((ext_vector_type(4)));

#define HD 256
#define TLEN 1000
#define NSTEP 999
#define BTILE 2

// ws layout (bf16 elements): W1R | W2R | W3R | W4R, fragment-ordered
#define W1R_OFF 0
#define W2R_OFF 16384
#define W3R_OFF 81920
#define W4R_OFF 147456
#define WS_ELEMS 151552

__device__ __forceinline__ void wg_barrier() {
  // LDS-only drain + barrier: do NOT force vmcnt(0) like __syncthreads does,
  // so the z-prefetch / out-stores stay in flight across layer barriers.
  asm volatile("s_waitcnt lgkmcnt(0)\n\ts_barrier" ::: "memory");
}

// Repack fp32 weights -> bf16 MFMA A-fragments in ws (r4 layout, unchanged).
// Fragment element for (w,kb,tt,lane,j): k = kb*32 + (lane>>4)*8 + j ; n = w*32 + tt*16 + (lane&15)
// value = W[k][n] (b1 folded into W1 padded row k==48).
__global__ void prep_weights(const float* __restrict__ W1, const float* __restrict__ b1,
                             const float* __restrict__ W2, const float* __restrict__ W3,
                             const float* __restrict__ W4, __bf16* __restrict__ ws) {
  int tid = blockIdx.x * blockDim.x + threadIdx.x;
  if (tid >= WS_ELEMS) return;
  float val = 0.0f;
  if (tid < W2R_OFF) {                       // W1R: 8w x 2kb x 2tt x 64lane x 8j
    int t = tid;
    int j = t & 7, lane = (t >> 3) & 63, tt = (t >> 9) & 1, kb = (t >> 10) & 1, w = (t >> 11) & 7;
    int k = kb * 32 + ((lane >> 4) * 8) + j;
    int n = w * 32 + tt * 16 + (lane & 15);
    if (k < 48) val = W1[k * HD + n];
    else if (k == 48) val = b1[n];           // bias folded via constant-1 input at k=48
  } else if (tid < W3R_OFF) {                // W2R: 8w x 8kb x 2tt x 64 x 8
    int t = tid - W2R_OFF;
    int j = t & 7, lane = (t >> 3) & 63, tt = (t >> 9) & 1, kb = (t >> 10) & 7, w = (t >> 13) & 7;
    int k = kb * 32 + ((lane >> 4) * 8) + j;
    int n = w * 32 + tt * 16 + (lane & 15);
    val = W2[k * HD + n];
  } else if (tid < W4R_OFF) {                // W3R
    int t = tid - W3R_OFF;
    int j = t & 7, lane = (t >> 3) & 63, tt = (t >> 9) & 1, kb = (t >> 10) & 7, w = (t >> 13) & 7;
    int k = kb * 32 + ((lane >> 4) * 8) + j;
    int n = w * 32 + tt * 16 + (lane & 15);
    val = W3[k * HD + n];
  } else {                                   // W4R: 8kb x 64 x 8, N padded 8->16 with zeros
    int t = tid - W4R_OFF;
    int j = t & 7, lane = (t >> 3) & 63, kb = (t >> 9) & 7;
    int k = kb * 32 + ((lane >> 4) * 8) + j;
    int n = lane & 15;
    val = (n < 8) ? W4[k * 8 + n] : 0.0f;
  }
  ws[tid] = (__bf16)val;
}

// r11 post-mortem: chain-split hurt (-7%, clean counters) — reverted; r4's
// single 8-deep chain restored. This round's ONE change: co-resident blocks.
//   BTILE 4 -> 2, grid 256 -> 512 => TWO independent blocks per CU
//   (4 waves/SIMD). The two blocks' barriers are independent, so one block's
//   barrier/LDS-latency bubbles (r4: ~21% idle, both pipes <50%) are filled
//   by the other block's waves. Per-block instruction stream, register set
//   (128 VGPR cap pinned via __launch_bounds__(512,4)), and LDS pattern are
//   byte-identical to r4 — this is the only untried TLP axis that adds no
//   register pressure and no new LDS access pattern (r6's conflict trap).
__global__ __launch_bounds__(512, 4) void ode_main(
    const float* __restrict__ t_g, const float* __restrict__ x_g,
    const float* __restrict__ z_g, const float* __restrict__ ev_g,
    const float* __restrict__ zj_g, const float* __restrict__ b2_g,
    const float* __restrict__ b3_g, const float* __restrict__ b4_g,
    const __bf16* __restrict__ ws, float* __restrict__ out) {
  __shared__ __align__(16) __bf16 h_a[16 * 264];   // 16 rows kept (2 live), row 528B
  __shared__ __align__(16) __bf16 h_b[16 * 264];
  __shared__ __align__(16) float p4[8 * 16 * 8];   // [wave][bcol][dim]
  __shared__ __align__(16) float x_cur[16 * 12];
  __shared__ __align__(16) float z_eff[16 * 12];
  __shared__ __align__(16) float x0s[16 * 12];
  __shared__ __align__(16) float z0s[16 * 12];
  __shared__ __align__(16) float zjs[16 * 12];
  __shared__ float evs[16];

  const int tid  = threadIdx.x;
  const int lane = tid & 63;
  const int wid  = tid >> 6;     // 8 waves; wave w owns hidden cols [32w, 32w+32)
  const int bcol = lane & 15;    // B/C-operand column; batch row if < BTILE, dead otherwise
  const int q    = lane >> 4;    // quad
  const int b0   = blockIdx.x * BTILE;
  const bool live = bcol < BTILE;

  // ---- stage per-batch constants (rows >= BTILE zeroed: dead cols stay exact 0) ----
  if (tid < 128) {
    int m = tid >> 3, d = tid & 7;
    if (m < BTILE) {
      size_t gb = (size_t)(b0 + m);
      float x0 = x_g[gb * (TLEN * 8) + d];
      float z0 = z_g[gb * (TLEN * 8) + d];
      x0s[m * 12 + d] = x0;
      z0s[m * 12 + d] = z0;
      x_cur[m * 12 + d] = x0;
      zjs[m * 12 + d] = zj_g[gb * 8 + d];
      out[gb * (TLEN * 8) + d] = x0;         // sol[:,0] = x0
      if (d == 0) evs[m] = ev_g[gb];
    } else {
      x0s[m * 12 + d] = 0.f;
      z0s[m * 12 + d] = 0.f;
      x_cur[m * 12 + d] = 0.f;
      zjs[m * 12 + d] = 0.f;
      if (d == 0) evs[m] = 0.f;
    }
  }
  __syncthreads();

  if (tid < 128) {  // z_eff for step 0 (rows >= BTILE resolve to 0)
    int m = tid >> 3, d = tid & 7;
    float t0 = t_g[0];
    z_eff[m * 12 + d] = (t0 >= evs[m]) ? zjs[m * 12 + d] : z0s[m * 12 + d];
  }

  // ---- resident weight fragments (A-operand layout) ----
  const bf16x8* wsv = (const bf16x8*)ws;
  bf16x8 w1f[2][2], w2f[8][2], w3f[8][2];
#pragma unroll
  for (int kb = 0; kb < 2; ++kb)
#pragma unroll
    for (int tt = 0; tt < 2; ++tt)
      w1f[kb][tt] = wsv[(W1R_OFF / 8) + ((wid * 2 + kb) * 2 + tt) * 64 + lane];
#pragma unroll
  for (int kb = 0; kb < 8; ++kb)
#pragma unroll
    for (int tt = 0; tt < 2; ++tt) {
      w2f[kb][tt] = wsv[(W2R_OFF / 8) + ((wid * 8 + kb) * 2 + tt) * 64 + lane];
      w3f[kb][tt] = wsv[(W3R_OFF / 8) + ((wid * 8 + kb) * 2 + tt) * 64 + lane];
    }
  // W4 k-slice for this wave: k in [32*wid, 32*wid+32)
  bf16x8 w4f = wsv[(W4R_OFF / 8) + wid * 64 + lane];

  // biases as C-init: lane's 4 C rows are hidden n = wid*32 + tt*16 + q*4 + e
  f32x4 b2v[2], b3v[2];
#pragma unroll
  for (int tt = 0; tt < 2; ++tt) {
    int n0 = wid * 32 + tt * 16 + q * 4;
    b2v[tt] = *(const f32x4*)(b2_g + n0);
    b3v[tt] = *(const f32x4*)(b3_g + n0);
  }
  float b4l = (tid < 64) ? b4_g[tid & 7] : 0.0f;

  // wave-2 personals (z_eff producer): lanes 0..BTILE*4-1 cover (m 0..BTILE-1) x (d pairs)
  const int m1 = lane >> 2;          // batch row
  const int d0 = (lane & 3) * 2;
  float2 zjf = make_float2(0.f, 0.f);
  float ev1 = 0.f;
  const bool zprod = (wid == 2) && (lane < BTILE * 4);
  if (zprod) {
    zjf.x = zjs[m1 * 12 + d0];
    zjf.y = zjs[m1 * 12 + d0 + 1];
    ev1 = evs[m1];
  }

  // layer-1 per-lane B-frag constants:
  // q=0: k=0..7   -> x0 (const)          q=1: k=8..15  -> z0 (const)
  // q=2: k=16..23 -> x_cur - x0          q=3: k=24..31 -> z_eff - z0
  f32x4 sub0, sub1;
  bf16x8 a0c;
  {
    const float* base = ((q & 1) ? z0s : x0s) + bcol * 12;
    f32x4 r0 = *(const f32x4*)(base);
    f32x4 r1 = *(const f32x4*)(base + 4);
    sub0 = r0; sub1 = r1;
#pragma unroll
    for (int e = 0; e < 4; ++e) { a0c[e] = (__bf16)r0[e]; a0c[e + 4] = (__bf16)r1[e]; }
  }
  bf16x8 zf;
#pragma unroll
  for (int e = 0; e < 8; ++e) zf[e] = (__bf16)0.f;
  bf16x8 k48f = zf;
  k48f[0] = (__bf16)1.0f;  // constant-1 input at padded k=48 -> adds b1

  __syncthreads();

  float tc = t_g[0];

  // persistent masked-read destinations: dead lanes keep zeros forever.
  bf16x8 bfr[8];
#pragma unroll
  for (int kb = 0; kb < 8; ++kb) bfr[kb] = zf;
  bf16x8 h4r = zf;

  auto layer = [&](const __bf16* src, __bf16* dst, const bf16x8 (*wf)[2], const f32x4* bv) {
    const bf16x8* hp = (const bf16x8*)src;
    if (live) {   // masked reads: dead lanes generate no LDS traffic
#pragma unroll
      for (int kb = 0; kb < 8; ++kb) bfr[kb] = hp[bcol * 33 + kb * 4 + q];  // ds_read_b128 x8
    }
#pragma unroll
    for (int tt = 0; tt < 2; ++tt) {
      f32x4 c = bv[tt];
#pragma unroll
      for (int kb = 0; kb < 8; ++kb)
        c = __builtin_amdgcn_mfma_f32_16x16x32_bf16(wf[kb][tt], bfr[kb], c, 0, 0, 0);
      union { __bf16 h4[4]; unsigned long long u; } pk;
#pragma unroll
      for (int e = 0; e < 4; ++e) {
        float v = c[e];
        v = (v > 0.f) ? v : (__expf(v) - 1.0f);  // ELU
        pk.h4[e] = (__bf16)v;
      }
      // 4 consecutive hidden cols for batch bcol -> one ds_write_b64
      if (live)
        *(unsigned long long*)(dst + bcol * 264 + wid * 32 + tt * 16 + q * 4) = pk.u;
    }
  };

#pragma unroll 1
  for (int i = 0; i < NSTEP; ++i) {
    float tn = t_g[i + 1];
    float2 zpre = make_float2(0.f, 0.f);
    if (zprod)  // prefetch z[:, i+1]; consumed in phase 4 of this step
      zpre = *(const float2*)(z_g + ((size_t)(b0 + m1) * TLEN + (i + 1)) * 8 + d0);

    // ---- phase 1: layer 1 (K padded 48->64, bias via k=48) ----
    {
      const float* rp = ((q & 1) ? z_eff : x_cur) + bcol * 12;
      f32x4 r0 = *(const f32x4*)(rp);
      f32x4 r1 = *(const f32x4*)(rp + 4);
      bf16x8 f0, f1;
      if (q < 2) {
        f0 = a0c;
#pragma unroll
        for (int e = 0; e < 4; ++e) { f1[e] = (__bf16)r0[e]; f1[e + 4] = (__bf16)r1[e]; }
      } else {
#pragma unroll
        for (int e = 0; e < 4; ++e) {
          f0[e] = (__bf16)(r0[e] - sub0[e]);
          f0[e + 4] = (__bf16)(r1[e] - sub1[e]);
        }
        f1 = (q == 2) ? k48f : zf;
      }
#pragma unroll
      for (int tt = 0; tt < 2; ++tt) {
        f32x4 c = {0.f, 0.f, 0.f, 0.f};
        c = __builtin_amdgcn_mfma_f32_16x16x32_bf16(w1f[0][tt], f0, c, 0, 0, 0);
        c = __builtin_amdgcn_mfma_f32_16x16x32_bf16(w1f[1][tt], f1, c, 0, 0, 0);
        union { __bf16 h4[4]; unsigned long long u; } pk;
#pragma unroll
        for (int e = 0; e < 4; ++e) {
          float v = c[e];
          v = (v > 0.f) ? v : (__expf(v) - 1.0f);
          pk.h4[e] = (__bf16)v;
        }
        if (live)
          *(unsigned long long*)(h_a + bcol * 264 + wid * 32 + tt * 16 + q * 4) = pk.u;
      }
    }
    wg_barrier();
    layer(h_a, h_b, w2f, b2v);   // phase 2: layer 2
    wg_barrier();
    layer(h_b, h_a, w3f, b3v);   // phase 3: layer 3 (h3 -> h_a)

    // ---- phase 3b (fused, no barrier): layer-4 partial on OWN 32 columns ----
    {
      const bf16x8* hp = (const bf16x8*)h_a;
      if (live) h4r = hp[bcol * 33 + wid * 4 + q];
      f32x4 c = {0.f, 0.f, 0.f, 0.f};
      c = __builtin_amdgcn_mfma_f32_16x16x32_bf16(w4f, h4r, c, 0, 0, 0);
      if (q < 2 && live)  // valid out rows n = q*4+e < 8
        *(f32x4*)(p4 + wid * 128 + bcol * 8 + q * 4) = c;
    }
    wg_barrier();

    // ---- phase 4: reduce + Euler (wave 0, rows < BTILE), z_eff(i+1) (wave 2) ----
    float dt = tn - tc;
    if (tid < 64) {
      int m = tid >> 3, d = tid & 7;
      if (m < BTILE) {                 // live batch rows only; rows >= BTILE stay 0
        float s = b4l;
#pragma unroll
        for (int j = 0; j < 8; ++j) s += p4[j * 128 + m * 8 + d];
        float xn = x_cur[m * 12 + d] + dt * s;
        x_cur[m * 12 + d] = xn;
        out[(size_t)(b0 + m) * (TLEN * 8) + (size_t)(i + 1) * 8 + d] = xn;
      }
    } else if (zprod) {
      bool jmp = (tn >= ev1);
      float2 zev = make_float2(jmp ? zjf.x : zpre.x, jmp ? zjf.y : zpre.y);
      *(float2*)(z_eff + m1 * 12 + d0) = zev;
    }
    tc = tn;
    wg_barrier();
  }
}

extern "C" void kernel_launch(void* const* d_in, const int* in_sizes, int n_in,
                              void* d_out, int out_size, void* d_ws, size_t ws_size,
                              hipStream_t stream) {
  const float* t  = (const float*)d_in[0];
  const float* x  = (const float*)d_in[1];
  const float* z  = (const float*)d_in[2];
  const float* ev = (const float*)d_in[3];
  const float* zj = (const float*)d_in[4];
  const float* W1 = (const float*)d_in[5];
  const float* b1 = (const float*)d_in[6];
  const float* W2 = (const float*)d_in[7];
  const float* b2 = (const float*)d_in[8];
  const float* W3 = (const float*)d_in[9];
  const float* b3 = (const float*)d_in[10];
  const float* W4 = (const float*)d_in[11];
  const float* b4 = (const float*)d_in[12];
  __bf16* ws = (__bf16*)d_ws;
  float* out = (float*)d_out;

  prep_weights<<<592, 256, 0, stream>>>(W1, b1, W2, W3, W4, ws);
  ode_main<<<512, 512, 0, stream>>>(t, x, z, ev, zj, b2, b3, b4, ws, out);
}

// Round 13
// 1594.672 us; speedup vs baseline: 9.7226x; 9.7226x over previous
//
#include <hip/hip_runtime.h>
#include <cstdint>
#include <cstddef>

typedef __bf16 bf16x8 __attribute__((ext_vector_type(8)));
typedef float f32x4 __attribute__((ext_vector_type(4)));

#define HD 256
#define TLEN 1000
#define NSTEP 999
#define BTILE 4

// ws layout (bf16 elements): W1F | W1C | W2R | W3R | W4R, fragment-ordered.
// W1F+W1C exactly fill r4's old W1R region; W2R/W3R/W4R offsets unchanged.
#define W1F_OFF 0
#define W1C_OFF 8192
#define W2R_OFF 16384
#define W3R_OFF 81920
#define W4R_OFF 147456
#define WS_ELEMS 151552

__device__ __forceinline__ void wg_barrier() {
  // LDS-only drain + barrier: do NOT force vmcnt(0) like __syncthreads does,
  // so the z-prefetch / out-stores stay in flight across layer barriers.
  asm volatile("s_waitcnt lgkmcnt(0)\n\ts_barrier" ::: "memory");
}

// Repack fp32 weights -> bf16 MFMA A-fragments in ws.
// Layer-1 algebraic fold (verified r1/r2/r7, absmax 0.25):
//   h1_pre = x*W1x + z_eff*W1z + c1
//   W1F: k0-7  = W1x = W1[16+k]+W1[32+k]
//        k8-15 = W1z = W1[24+(k-8)]+W1[40+(k-8)], k16-31 = 0
//   W1C (consumed ONCE pre-loop into c1init):
//        k0-7  = W1[k]-W1[16+k], k8-15 = W1[8+(k-8)]-W1[24+(k-8)],
//        k16   = b1 (fed by constant-1), rest 0
// W2/W3/W4 fragment layout unchanged from r4:
//   k = kb*32 + (lane>>4)*8 + j ; n = w*32 + tt*16 + (lane&15)
__global__ void prep_weights(const float* __restrict__ W1, const float* __restrict__ b1,
                             const float* __restrict__ W2, const float* __restrict__ W3,
                             const float* __restrict__ W4, __bf16* __restrict__ ws) {
  int tid = blockIdx.x * blockDim.x + threadIdx.x;
  if (tid >= WS_ELEMS) return;
  float val = 0.0f;
  if (tid < W1C_OFF) {                       // W1F: 8w x 2tt x 64lane x 8j
    int t = tid;
    int j = t & 7, lane = (t >> 3) & 63, tt = (t >> 9) & 1, w = (t >> 10) & 7;
    int k = ((lane >> 4) * 8) + j;
    int n = w * 32 + tt * 16 + (lane & 15);
    if (k < 8) val = W1[(16 + k) * HD + n] + W1[(32 + k) * HD + n];
    else if (k < 16) { int d = k - 8; val = W1[(24 + d) * HD + n] + W1[(40 + d) * HD + n]; }
  } else if (tid < W2R_OFF) {                // W1C
    int t = tid - W1C_OFF;
    int j = t & 7, lane = (t >> 3) & 63, tt = (t >> 9) & 1, w = (t >> 10) & 7;
    int k = ((lane >> 4) * 8) + j;
    int n = w * 32 + tt * 16 + (lane & 15);
    if (k < 8) val = W1[k * HD + n] - W1[(16 + k) * HD + n];
    else if (k < 16) { int d = k - 8; val = W1[(8 + d) * HD + n] - W1[(24 + d) * HD + n]; }
    else if (k == 16) val = b1[n];
  } else if (tid < W3R_OFF) {                // W2R: 8w x 8kb x 2tt x 64 x 8
    int t = tid - W2R_OFF;
    int j = t & 7, lane = (t >> 3) & 63, tt = (t >> 9) & 1, kb = (t >> 10) & 7, w = (t >> 13) & 7;
    int k = kb * 32 + ((lane >> 4) * 8) + j;
    int n = w * 32 + tt * 16 + (lane & 15);
    val = W2[k * HD + n];
  } else if (tid < W4R_OFF) {                // W3R
    int t = tid - W3R_OFF;
    int j = t & 7, lane = (t >> 3) & 63, tt = (t >> 9) & 1, kb = (t >> 10) & 7, w = (t >> 13) & 7;
    int k = kb * 32 + ((lane >> 4) * 8) + j;
    int n = w * 32 + tt * 16 + (lane & 15);
    val = W3[k * HD + n];
  } else {                                   // W4R: 8kb x 64 x 8, N padded 8->16 with zeros
    int t = tid - W4R_OFF;
    int j = t & 7, lane = (t >> 3) & 63, kb = (t >> 9) & 7;
    int k = kb * 32 + ((lane >> 4) * 8) + j;
    int n = lane & 15;
    val = (n < 8) ? W4[k * 8 + n] : 0.0f;
  }
  ws[tid] = (__bf16)val;
}

// r12 post-mortem: co-residency is structurally unaffordable (weights ~256
// regs/wave in the unified file; forced 128-cap spilled 56 GB of scratch).
// This version = r4 champion with ONE register-NEGATIVE change (net -16):
// layer-1 fold. Phase 1: 2 MFMAs (was 4), no subtract path, c1 (x0/z0/b1
// terms) folded once pre-loop into the MFMA C-initializer via W1C.
// Everything else byte-identical to r4.
__global__ __launch_bounds__(512, 2) void ode_main(
    const float* __restrict__ t_g, const float* __restrict__ x_g,
    const float* __restrict__ z_g, const float* __restrict__ ev_g,
    const float* __restrict__ zj_g, const float* __restrict__ b2_g,
    const float* __restrict__ b3_g, const float* __restrict__ b4_g,
    const __bf16* __restrict__ ws, float* __restrict__ out) {
  __shared__ __align__(16) __bf16 h_a[16 * 264];   // 16 rows kept (4 live), row 528B
  __shared__ __align__(16) __bf16 h_b[16 * 264];
  __shared__ __align__(16) float p4[8 * 16 * 8];   // [wave][bcol][dim]
  __shared__ __align__(16) float x_cur[16 * 12];
  __shared__ __align__(16) float z_eff[16 * 12];
  __shared__ __align__(16) float x0s[16 * 12];
  __shared__ __align__(16) float z0s[16 * 12];
  __shared__ __align__(16) float zjs[16 * 12];
  __shared__ float evs[16];

  const int tid  = threadIdx.x;
  const int lane = tid & 63;
  const int wid  = tid >> 6;     // 8 waves; wave w owns hidden cols [32w, 32w+32)
  const int bcol = lane & 15;    // B/C-operand column; batch row if < BTILE, dead otherwise
  const int q    = lane >> 4;    // quad
  const int b0   = blockIdx.x * BTILE;
  const bool live = bcol < BTILE;

  // ---- stage per-batch constants (rows >= BTILE zeroed: dead cols stay exact 0) ----
  if (tid < 128) {
    int m = tid >> 3, d = tid & 7;
    if (m < BTILE) {
      size_t gb = (size_t)(b0 + m);
      float x0 = x_g[gb * (TLEN * 8) + d];
      float z0 = z_g[gb * (TLEN * 8) + d];
      x0s[m * 12 + d] = x0;
      z0s[m * 12 + d] = z0;
      x_cur[m * 12 + d] = x0;
      zjs[m * 12 + d] = zj_g[gb * 8 + d];
      out[gb * (TLEN * 8) + d] = x0;         // sol[:,0] = x0
      if (d == 0) evs[m] = ev_g[gb];
    } else {
      x0s[m * 12 + d] = 0.f;
      z0s[m * 12 + d] = 0.f;
      x_cur[m * 12 + d] = 0.f;
      zjs[m * 12 + d] = 0.f;
      if (d == 0) evs[m] = 0.f;
    }
  }
  __syncthreads();

  if (tid < 128) {  // z_eff for step 0 (rows >= BTILE resolve to 0)
    int m = tid >> 3, d = tid & 7;
    float t0 = t_g[0];
    z_eff[m * 12 + d] = (t0 >= evs[m]) ? zjs[m * 12 + d] : z0s[m * 12 + d];
  }

  // ---- resident weight fragments (A-operand layout) ----
  const bf16x8* wsv = (const bf16x8*)ws;
  bf16x8 w1ff[2], w2f[8][2], w3f[8][2];
#pragma unroll
  for (int tt = 0; tt < 2; ++tt)
    w1ff[tt] = wsv[(W1F_OFF / 8) + (wid * 2 + tt) * 64 + lane];
#pragma unroll
  for (int kb = 0; kb < 8; ++kb)
#pragma unroll
    for (int tt = 0; tt < 2; ++tt) {
      w2f[kb][tt] = wsv[(W2R_OFF / 8) + ((wid * 8 + kb) * 2 + tt) * 64 + lane];
      w3f[kb][tt] = wsv[(W3R_OFF / 8) + ((wid * 8 + kb) * 2 + tt) * 64 + lane];
    }
  // W4 k-slice for this wave: k in [32*wid, 32*wid+32)
  bf16x8 w4f = wsv[(W4R_OFF / 8) + wid * 64 + lane];

  // biases as C-init: lane's 4 C rows are hidden n = wid*32 + tt*16 + q*4 + e
  f32x4 b2v[2], b3v[2];
#pragma unroll
  for (int tt = 0; tt < 2; ++tt) {
    int n0 = wid * 32 + tt * 16 + q * 4;
    b2v[tt] = *(const f32x4*)(b2_g + n0);
    b3v[tt] = *(const f32x4*)(b3_g + n0);
  }
  float b4l = (tid < 64) ? b4_g[tid & 7] : 0.0f;

  // wave-2 personals (z_eff producer): lanes 0..BTILE*4-1 cover (m 0..BTILE-1) x (d pairs)
  const int m1 = lane >> 2;          // batch row
  const int d0 = (lane & 3) * 2;
  float2 zjf = make_float2(0.f, 0.f);
  float ev1 = 0.f;
  const bool zprod = (wid == 2) && (lane < BTILE * 4);
  if (zprod) {
    zjf.x = zjs[m1 * 12 + d0];
    zjf.y = zjs[m1 * 12 + d0 + 1];
    ev1 = evs[m1];
  }

  bf16x8 zf;
#pragma unroll
  for (int e = 0; e < 8; ++e) zf[e] = (__bf16)0.f;

  // ---- c1init: step-invariant layer-1 term via ONE-SHOT MFMA on W1C ----
  // cfrag: q0 = x0 (8 dims), q1 = z0, q2 elem0 = 1 (b1 row at k=16), q3 = 0
  f32x4 c1init[2];
  {
    bf16x8 cfrag = zf;
    if (q == 0) {
      const float* xp = x0s + bcol * 12;
#pragma unroll
      for (int e = 0; e < 4; ++e) { cfrag[e] = (__bf16)xp[e]; cfrag[e + 4] = (__bf16)xp[e + 4]; }
    } else if (q == 1) {
      const float* zp = z0s + bcol * 12;
#pragma unroll
      for (int e = 0; e < 4; ++e) { cfrag[e] = (__bf16)zp[e]; cfrag[e + 4] = (__bf16)zp[e + 4]; }
    } else if (q == 2) {
      cfrag[0] = (__bf16)1.0f;
    }
    f32x4 z4 = {0.f, 0.f, 0.f, 0.f};
#pragma unroll
    for (int tt = 0; tt < 2; ++tt) {
      bf16x8 w1cf = wsv[(W1C_OFF / 8) + (wid * 2 + tt) * 64 + lane];
      c1init[tt] = __builtin_amdgcn_mfma_f32_16x16x32_bf16(w1cf, cfrag, z4, 0, 0, 0);
    }
  }

  __syncthreads();

  float tc = t_g[0];

  // persistent masked-read destinations: dead lanes keep zeros forever.
  bf16x8 bfr[8];
#pragma unroll
  for (int kb = 0; kb < 8; ++kb) bfr[kb] = zf;
  bf16x8 h4r = zf;

  auto layer = [&](const __bf16* src, __bf16* dst, const bf16x8 (*wf)[2], const f32x4* bv) {
    const bf16x8* hp = (const bf16x8*)src;
    if (live) {   // masked reads: dead lanes generate no LDS traffic
#pragma unroll
      for (int kb = 0; kb < 8; ++kb) bfr[kb] = hp[bcol * 33 + kb * 4 + q];  // ds_read_b128 x8
    }
#pragma unroll
    for (int tt = 0; tt < 2; ++tt) {
      f32x4 c = bv[tt];
#pragma unroll
      for (int kb = 0; kb < 8; ++kb)
        c = __builtin_amdgcn_mfma_f32_16x16x32_bf16(wf[kb][tt], bfr[kb], c, 0, 0, 0);
      union { __bf16 h4[4]; unsigned long long u; } pk;
#pragma unroll
      for (int e = 0; e < 4; ++e) {
        float v = c[e];
        v = (v > 0.f) ? v : (__expf(v) - 1.0f);  // ELU
        pk.h4[e] = (__bf16)v;
      }
      // 4 consecutive hidden cols for batch bcol -> one ds_write_b64
      if (live)
        *(unsigned long long*)(dst + bcol * 264 + wid * 32 + tt * 16 + q * 4) = pk.u;
    }
  };

#pragma unroll 1
  for (int i = 0; i < NSTEP; ++i) {
    float tn = t_g[i + 1];
    float2 zpre = make_float2(0.f, 0.f);
    if (zprod)  // prefetch z[:, i+1]; consumed in phase 4 of this step
      zpre = *(const float2*)(z_g + ((size_t)(b0 + m1) * TLEN + (i + 1)) * 8 + d0);

    // ---- phase 1: folded layer 1 — 2 MFMAs, C-init = c1init ----
    // B-frag: q0 = x_cur (k0-7), q1 = z_eff (k8-15), q2/q3 = 0
    {
      bf16x8 f = zf;
      if (q < 2) {
        const float* rp = ((q & 1) ? z_eff : x_cur) + bcol * 12;
        f32x4 r0 = *(const f32x4*)(rp);
        f32x4 r1 = *(const f32x4*)(rp + 4);
#pragma unroll
        for (int e = 0; e < 4; ++e) { f[e] = (__bf16)r0[e]; f[e + 4] = (__bf16)r1[e]; }
      }
#pragma unroll
      for (int tt = 0; tt < 2; ++tt) {
        f32x4 c = __builtin_amdgcn_mfma_f32_16x16x32_bf16(w1ff[tt], f, c1init[tt], 0, 0, 0);
        union { __bf16 h4[4]; unsigned long long u; } pk;
#pragma unroll
        for (int e = 0; e < 4; ++e) {
          float v = c[e];
          v = (v > 0.f) ? v : (__expf(v) - 1.0f);
          pk.h4[e] = (__bf16)v;
        }
        if (live)
          *(unsigned long long*)(h_a + bcol * 264 + wid * 32 + tt * 16 + q * 4) = pk.u;
      }
    }
    wg_barrier();
    layer(h_a, h_b, w2f, b2v);   // phase 2: layer 2
    wg_barrier();
    layer(h_b, h_a, w3f, b3v);   // phase 3: layer 3 (h3 -> h_a)

    // ---- phase 3b (fused, no barrier): layer-4 partial on OWN 32 columns ----
    {
      const bf16x8* hp = (const bf16x8*)h_a;
      if (live) h4r = hp[bcol * 33 + wid * 4 + q];
      f32x4 c = {0.f, 0.f, 0.f, 0.f};
      c = __builtin_amdgcn_mfma_f32_16x16x32_bf16(w4f, h4r, c, 0, 0, 0);
      if (q < 2 && live)  // valid out rows n = q*4+e < 8
        *(f32x4*)(p4 + wid * 128 + bcol * 8 + q * 4) = c;
    }
    wg_barrier();

    // ---- phase 4: reduce + Euler (wave 0, rows < BTILE), z_eff(i+1) (wave 2) ----
    float dt = tn - tc;
    if (tid < 64) {
      int m = tid >> 3, d = tid & 7;
      if (m < BTILE) {                 // live batch rows only; rows >= BTILE stay 0
        float s = b4l;
#pragma unroll
        for (int j = 0; j < 8; ++j) s += p4[j * 128 + m * 8 + d];
        float xn = x_cur[m * 12 + d] + dt * s;
        x_cur[m * 12 + d] = xn;
        out[(size_t)(b0 + m) * (TLEN * 8) + (size_t)(i + 1) * 8 + d] = xn;
      }
    } else if (zprod) {
      bool jmp = (tn >= ev1);
      float2 zev = make_float2(jmp ? zjf.x : zpre.x, jmp ? zjf.y : zpre.y);
      *(float2*)(z_eff + m1 * 12 + d0) = zev;
    }
    tc = tn;
    wg_barrier();
  }
}

extern "C" void kernel_launch(void* const* d_in, const int* in_sizes, int n_in,
                              void* d_out, int out_size, void* d_ws, size_t ws_size,
                              hipStream_t stream) {
  const float* t  = (const float*)d_in[0];
  const float* x  = (const float*)d_in[1];
  const float* z  = (const float*)d_in[2];
  const float* ev = (const float*)d_in[3];
  const float* zj = (const float*)d_in[4];
  const float* W1 = (const float*)d_in[5];
  const float* b1 = (const float*)d_in[6];
  const float* W2 = (const float*)d_in[7];
  const float* b2 = (const float*)d_in[8];
  const float* W3 = (const float*)d_in[9];
  const float* b3 = (const float*)d_in[10];
  const float* W4 = (const float*)d_in[11];
  const float* b4 = (const float*)d_in[12];
  __bf16* ws = (__bf16*)d_ws;
  float* out = (float*)d_out;

  prep_weights<<<592, 256, 0, stream>>>(W1, b1, W2, W3, W4, ws);
  ode_main<<<256, 512, 0, stream>>>(t, x, z, ev, zj, b2, b3, b4, ws, out);
}